// Round 8
// baseline (367.958 us; speedup 1.0000x reference)
//
#include <hip/hip_runtime.h>

// Problem constants (match reference setup_inputs)
#define BB 16
#define TT 32641
#define EE 128
#define LL (TT + EE - 1)             // 32768 = 2^15 groups
#define RT 64                        // rows per tile in pass 1
#define NTILES ((TT + RT - 1) / RT)  // 511 tiles per batch
#define GPT (RT + EE - 1)            // 191 group partials per tile
#define SLOT 192                     // stride: 191 G-partials + 1 Qw slot
#define NTH 256
#define P2_BLOCKS 256

typedef float vf4 __attribute__((ext_vector_type(4)));

// c(t) = |{(i,j): i+j==t, 0<=i<TT, 0<=j<EE}|  (TT >= EE)
__device__ __forceinline__ float groupWeight(int t) {
    int c = min(min(t + 1, EE), LL - t);
    return 1.0f / (float)c;
}

// Pass 1: one block per (tile, batch), reversed mapping (R7 win kept).
//  Phase A: async global->LDS staging via global_load_lds width=16:
//           per wave, 8 fire-and-forget 1-KB DMA instructions, no VGPR
//           round-trip, no ds_write. LDS layout is plain row-major, which
//           matches the instruction's wave-uniform-base + lane*16 rule.
//           Edge tile (nrows<RT) falls back to a plain copy (no OOB reads).
//  Phase B: thread d (<GPT) walks anti-diagonal d in LDS (conflict-free
//           b32 reads), accumulating G and q; w*q only for non-empty
//           diagonals (NaN guard, R6 lesson).
__global__ __launch_bounds__(NTH) void tc_pass1(const float* __restrict__ in,
                                                float* __restrict__ part) {
    __shared__ float lsum[RT * EE];        // 32 KB
    __shared__ float red[NTH / 64];
    const int tid  = threadIdx.x;
    const int lane = tid & 63;
    const int wv   = tid >> 6;
    const int k    = (NTILES - 1) - blockIdx.x;   // reversed tile order
    const int b    = (BB - 1) - blockIdx.y;       // reversed batch order
    const int r0   = k * RT;
    const int nrows = min(RT, TT - r0);

    const vf4* __restrict__ src = (const vf4*)(in + ((size_t)b * TT + r0) * EE);

    if (nrows == RT) {
        // wave wv owns float4 range [wv*512, wv*512+511]; 8 iters x 64 lanes.
        const vf4* gsrc = src + (wv * 512 + lane);
        #pragma unroll
        for (int u = 0; u < 8; ++u) {
            __builtin_amdgcn_global_load_lds(
                (const __attribute__((address_space(1))) void*)(gsrc + u * 64),
                (__attribute__((address_space(3))) void*)(&lsum[wv * 2048 + u * 256]),
                16, 0, 0);
        }
    } else {
        vf4* ldst = (vf4*)lsum;
        const int nvec = nrows * (EE / 4);
        for (int v = tid; v < nvec; v += NTH)
            ldst[v] = __builtin_nontemporal_load(&src[v]);
    }
    __syncthreads();   // compiler emits s_waitcnt vmcnt(0) before s_barrier

    float* __restrict__ base = part + ((size_t)b * NTILES + k) * SLOT;

    // Phase B: lane d reads lsum[i*EE + (d-i)]; consecutive lanes ->
    // consecutive LDS addresses -> conflict-free.
    float qw = 0.0f;
    if (tid < GPT) {
        const int d = tid;
        const int ilo = max(0, d - (EE - 1));
        const int ihi = min(nrows - 1, d);
        float g = 0.0f, q = 0.0f;
        for (int i = ilo; i <= ihi; ++i) {
            float x = lsum[i * EE + (d - i)];
            g += x;
            q += x * x;
        }
        base[d] = g;                       // zero when loop empty
        if (ihi >= ilo) qw = q * groupWeight(r0 + d);   // empty diag: t may be >= LL
    }

    // block-reduce qw -> slot GPT (non-atomic)
    #pragma unroll
    for (int o = 32; o > 0; o >>= 1) qw += __shfl_down(qw, o, 64);
    if ((tid & 63) == 0) red[tid >> 6] = qw;
    __syncthreads();
    if (tid == 0) base[GPT] = red[0] + red[1] + red[2] + red[3];
}

// Pass 2: S1 = sum over (b,t) of (G(b,t)*w(t))^2 from <=3 tile partials;
//         S2 = sum of per-tile w*q slots. Non-atomic block partials.
__global__ __launch_bounds__(NTH) void tc_pass2(const float* __restrict__ part,
                                                float* __restrict__ part2) {
    __shared__ float redA[NTH / 64], redB[NTH / 64];
    float s1 = 0.0f, s2 = 0.0f;
    const int N = BB * LL;
    for (int idx = blockIdx.x * NTH + threadIdx.x; idx < N; idx += gridDim.x * NTH) {
        const int t  = idx & (LL - 1);
        const int b  = idx >> 15;              // LL = 2^15
        const int k0 = t >> 6;                 // RT = 64
        float g = 0.0f;
        #pragma unroll
        for (int dk = 2; dk >= 0; --dk) {
            const int k = k0 - dk;
            const int d = t - (k << 6);
            if (k >= 0 && k < NTILES && d >= 0 && d < GPT)
                g += part[((size_t)b * NTILES + k) * SLOT + d];
        }
        const float m = g * groupWeight(t);
        s1 += m * m;
    }
    const int NS = BB * NTILES;
    for (int idx = blockIdx.x * NTH + threadIdx.x; idx < NS; idx += gridDim.x * NTH) {
        s2 += part[(size_t)idx * SLOT + GPT];
    }
    #pragma unroll
    for (int o = 32; o > 0; o >>= 1) {
        s1 += __shfl_down(s1, o, 64);
        s2 += __shfl_down(s2, o, 64);
    }
    if ((threadIdx.x & 63) == 0) { redA[threadIdx.x >> 6] = s1; redB[threadIdx.x >> 6] = s2; }
    __syncthreads();
    if (threadIdx.x == 0) {
        part2[blockIdx.x * 2 + 0] = redA[0] + redA[1] + redA[2] + redA[3];
        part2[blockIdx.x * 2 + 1] = redB[0] + redB[1] + redB[2] + redB[3];
    }
}

__global__ __launch_bounds__(NTH) void tc_final(const float* __restrict__ part2,
                                                float* __restrict__ out) {
    __shared__ float redA[NTH / 64], redB[NTH / 64];
    float s1 = 0.0f, s2 = 0.0f;
    for (int i = threadIdx.x; i < P2_BLOCKS; i += NTH) {
        s1 += part2[i * 2 + 0];
        s2 += part2[i * 2 + 1];
    }
    #pragma unroll
    for (int o = 32; o > 0; o >>= 1) {
        s1 += __shfl_down(s1, o, 64);
        s2 += __shfl_down(s2, o, 64);
    }
    if ((threadIdx.x & 63) == 0) { redA[threadIdx.x >> 6] = s1; redB[threadIdx.x >> 6] = s2; }
    __syncthreads();
    if (threadIdx.x == 0) {
        const float scale = (float)(0.1 / ((double)BB * (double)LL));
        out[0] = (redB[0] + redB[1] + redB[2] + redB[3]
                - (redA[0] + redA[1] + redA[2] + redA[3])) * scale;
    }
}

extern "C" void kernel_launch(void* const* d_in, const int* in_sizes, int n_in,
                              void* d_out, int out_size, void* d_ws, size_t ws_size,
                              hipStream_t stream) {
    const float* in = (const float*)d_in[0];
    float* part  = (float*)d_ws;                          // BB*NTILES*SLOT floats ~ 6.3 MB
    float* part2 = part + (size_t)BB * NTILES * SLOT;     // P2_BLOCKS*2 floats
    float* out   = (float*)d_out;

    dim3 g1(NTILES, BB);
    tc_pass1<<<g1, NTH, 0, stream>>>(in, part);
    tc_pass2<<<P2_BLOCKS, NTH, 0, stream>>>(part, part2);
    tc_final<<<1, NTH, 0, stream>>>(part2, out);
}

// Round 9
// 346.370 us; speedup vs baseline: 1.0623x; 1.0623x over previous
//
#include <hip/hip_runtime.h>

// Problem constants (match reference setup_inputs)
#define BB 16
#define TT 32641
#define EE 128
#define LL (TT + EE - 1)             // 32768 = 2^15 groups
#define RT 32                        // rows per tile (16 KB LDS -> 8 blocks/CU)
#define NTILES ((TT + RT - 1) / RT)  // 1021 tiles per batch
#define GPT (RT + EE - 1)            // 159 group partials per tile
#define SLOT 160                     // stride: 159 G-partials + 1 Qw slot
#define NTH 256
#define P2_BLOCKS 256

typedef float vf4 __attribute__((ext_vector_type(4)));

// c(t) = |{(i,j): i+j==t, 0<=i<TT, 0<=j<EE}|  (TT >= EE)
__device__ __forceinline__ float groupWeight(int t) {
    int c = min(min(t + 1, EE), LL - t);
    return 1.0f / (float)c;
}

// Pass 1: one block per (tile, batch), reversed mapping (R7 win), NT float4
// staging (R7 win; R8 showed DMA staging loses the nt behavior and regresses).
// RT=32 -> 16 KB LDS -> 8 resident blocks/CU (100% wave occupancy): the load
// phases of ~8 concurrent blocks cover the vmcnt-drain + LDS phase of others.
__global__ __launch_bounds__(NTH, 8) void tc_pass1(const float* __restrict__ in,
                                                   float* __restrict__ part) {
    __shared__ float lsum[RT * EE];        // 16 KB
    __shared__ float red[NTH / 64];
    const int tid = threadIdx.x;
    const int k   = (NTILES - 1) - blockIdx.x;   // reversed tile order
    const int b   = (BB - 1) - blockIdx.y;       // reversed batch order
    const int r0  = k * RT;
    const int nrows = min(RT, TT - r0);

    const vf4* __restrict__ src = (const vf4*)(in + ((size_t)b * TT + r0) * EE);
    vf4* __restrict__ ldst = (vf4*)lsum;

    if (nrows == RT) {
        // 1024 float4 per block; 4 per thread, all loads issued before writes
        vf4 x0 = __builtin_nontemporal_load(&src[tid + 0 * NTH]);
        vf4 x1 = __builtin_nontemporal_load(&src[tid + 1 * NTH]);
        vf4 x2 = __builtin_nontemporal_load(&src[tid + 2 * NTH]);
        vf4 x3 = __builtin_nontemporal_load(&src[tid + 3 * NTH]);
        ldst[tid + 0 * NTH] = x0;
        ldst[tid + 1 * NTH] = x1;
        ldst[tid + 2 * NTH] = x2;
        ldst[tid + 3 * NTH] = x3;
    } else {
        const int nvec = nrows * (EE / 4);
        for (int v = tid; v < nvec; v += NTH)
            ldst[v] = __builtin_nontemporal_load(&src[v]);
    }
    __syncthreads();

    float* __restrict__ base = part + ((size_t)b * NTILES + k) * SLOT;

    // Phase B: lane d walks anti-diagonal d: lsum[i*EE + (d-i)], consecutive
    // lanes -> consecutive LDS addresses -> conflict-free.
    float qw = 0.0f;
    if (tid < GPT) {
        const int d = tid;
        const int ilo = max(0, d - (EE - 1));
        const int ihi = min(nrows - 1, d);
        float g = 0.0f, q = 0.0f;
        for (int i = ilo; i <= ihi; ++i) {
            float x = lsum[i * EE + (d - i)];
            g += x;
            q += x * x;
        }
        base[d] = g;                       // zero when loop empty
        if (ihi >= ilo) qw = q * groupWeight(r0 + d);   // empty diag: t can be >= LL (NaN guard)
    }

    // block-reduce qw -> slot GPT (non-atomic)
    #pragma unroll
    for (int o = 32; o > 0; o >>= 1) qw += __shfl_down(qw, o, 64);
    if ((tid & 63) == 0) red[tid >> 6] = qw;
    __syncthreads();
    if (tid == 0) base[GPT] = red[0] + red[1] + red[2] + red[3];
}

// Pass 2: S1 = sum over (b,t) of (G(b,t)*w(t))^2 from <=5 tile partials;
//         S2 = sum of per-tile w*q slots. Non-atomic block partials.
__global__ __launch_bounds__(NTH) void tc_pass2(const float* __restrict__ part,
                                                float* __restrict__ part2) {
    __shared__ float redA[NTH / 64], redB[NTH / 64];
    float s1 = 0.0f, s2 = 0.0f;
    const int N = BB * LL;
    for (int idx = blockIdx.x * NTH + threadIdx.x; idx < N; idx += gridDim.x * NTH) {
        const int t  = idx & (LL - 1);
        const int b  = idx >> 15;              // LL = 2^15
        const int k0 = t >> 5;                 // RT = 32
        float g = 0.0f;
        #pragma unroll
        for (int dk = 4; dk >= 0; --dk) {
            const int k = k0 - dk;
            const int d = t - (k << 5);        // = (t&31) + 32*dk >= 0
            if (k >= 0 && k < NTILES && d < GPT)
                g += part[((size_t)b * NTILES + k) * SLOT + d];
        }
        const float m = g * groupWeight(t);
        s1 += m * m;
    }
    const int NS = BB * NTILES;
    for (int idx = blockIdx.x * NTH + threadIdx.x; idx < NS; idx += gridDim.x * NTH) {
        s2 += part[(size_t)idx * SLOT + GPT];
    }
    #pragma unroll
    for (int o = 32; o > 0; o >>= 1) {
        s1 += __shfl_down(s1, o, 64);
        s2 += __shfl_down(s2, o, 64);
    }
    if ((threadIdx.x & 63) == 0) { redA[threadIdx.x >> 6] = s1; redB[threadIdx.x >> 6] = s2; }
    __syncthreads();
    if (threadIdx.x == 0) {
        part2[blockIdx.x * 2 + 0] = redA[0] + redA[1] + redA[2] + redA[3];
        part2[blockIdx.x * 2 + 1] = redB[0] + redB[1] + redB[2] + redB[3];
    }
}

__global__ __launch_bounds__(NTH) void tc_final(const float* __restrict__ part2,
                                                float* __restrict__ out) {
    __shared__ float redA[NTH / 64], redB[NTH / 64];
    float s1 = 0.0f, s2 = 0.0f;
    for (int i = threadIdx.x; i < P2_BLOCKS; i += NTH) {
        s1 += part2[i * 2 + 0];
        s2 += part2[i * 2 + 1];
    }
    #pragma unroll
    for (int o = 32; o > 0; o >>= 1) {
        s1 += __shfl_down(s1, o, 64);
        s2 += __shfl_down(s2, o, 64);
    }
    if ((threadIdx.x & 63) == 0) { redA[threadIdx.x >> 6] = s1; redB[threadIdx.x >> 6] = s2; }
    __syncthreads();
    if (threadIdx.x == 0) {
        const float scale = (float)(0.1 / ((double)BB * (double)LL));
        out[0] = (redB[0] + redB[1] + redB[2] + redB[3]
                - (redA[0] + redA[1] + redA[2] + redA[3])) * scale;
    }
}

extern "C" void kernel_launch(void* const* d_in, const int* in_sizes, int n_in,
                              void* d_out, int out_size, void* d_ws, size_t ws_size,
                              hipStream_t stream) {
    const float* in = (const float*)d_in[0];
    float* part  = (float*)d_ws;                          // BB*NTILES*SLOT floats ~ 10.5 MB
    float* part2 = part + (size_t)BB * NTILES * SLOT;     // P2_BLOCKS*2 floats
    float* out   = (float*)d_out;

    dim3 g1(NTILES, BB);
    tc_pass1<<<g1, NTH, 0, stream>>>(in, part);
    tc_pass2<<<P2_BLOCKS, NTH, 0, stream>>>(part, part2);
    tc_final<<<1, NTH, 0, stream>>>(part2, out);
}